// Round 9
// baseline (202.471 us; speedup 1.0000x reference)
//
#include <hip/hip_runtime.h>
#include <math.h>

#define TT 2048
#define LK 769
#define NF 20
#define NS 128
#define NB 18

// ---------------------------------------------------------------------------
// Kernel A: symmetric FIR conv (fwd+bwd averaged == conv with symmetrized
// taps), reflect padding folded into index mirror.
// One wg per (signal, filter-PAIR): pha band p + amp band (9-p) share the
// same LDS signal window. R9: 8 taps/iter with a 3-register float4 rolling
// window and explicit next-iteration prefetch of taps+window (8 ds_read_b128
// per iter, prefetch distance ~130+ issue cycles >= LDS latency). Tap order
// per output unchanged (extra range-rounding taps are exact zeros).
// ---------------------------------------------------------------------------
__global__ __launch_bounds__(256) void conv_kernel(const float* __restrict__ x,
                                                   const float* __restrict__ ker,
                                                   float* __restrict__ filt) {
  __shared__ __align__(16) float w[2832];   // spad[384..3200) + zero tail
  __shared__ __align__(16) float hs1[784];  // symmetrized pha filter
  __shared__ __align__(16) float hs2[784];  // symmetrized amp filter
  __shared__ int red[4][4];
  const int tid = threadIdx.x;
  const int ord = blockIdx.x;
  const int p = ord / NS;                   // 0..9, longest pair first
  const int n = ord % NS;
  const int o1 = p;                          // pha band
  const int o2 = 10 + (9 - p);               // amp band (short with long)
  const float* xr = x + n * TT;
  for (int j = tid; j < 2832; j += 256) {
    float v = 0.f;
    if (j < 2816) {
      int m = j - 384;              // spad[j+384] -> original index (j+384)-768
      if (m < 0) m = -m;            // reflect (edge excluded)
      if (m > 2047) m = 4094 - m;
      v = xr[m];
    }
    w[j] = v;
  }
  const float* kr1 = ker + o1 * LK;
  const float* kr2 = ker + o2 * LK;
  int k0 = 784, k1 = 0, m0 = 784, m1 = 0;
  for (int k = tid; k < 784; k += 256) {
    float v1 = 0.f, v2 = 0.f;
    if (k < LK) {
      v1 = 0.5f * (kr1[k] + kr1[LK - 1 - k]);
      v2 = 0.5f * (kr2[k] + kr2[LK - 1 - k]);
    }
    hs1[k] = v1;
    hs2[k] = v2;
    if (v1 != 0.f) { k0 = min(k0, k); k1 = max(k1, k + 1); }
    if (v2 != 0.f) { m0 = min(m0, k); m1 = max(m1, k + 1); }
  }
#pragma unroll
  for (int off = 32; off > 0; off >>= 1) {
    k0 = min(k0, __shfl_down(k0, off));
    k1 = max(k1, __shfl_down(k1, off));
    m0 = min(m0, __shfl_down(m0, off));
    m1 = max(m1, __shfl_down(m1, off));
  }
  const int wid = tid >> 6;
  if ((tid & 63) == 0) { red[wid][0] = k0; red[wid][1] = k1; red[wid][2] = m0; red[wid][3] = m1; }
  __syncthreads();
  k0 = min(min(red[0][0], red[1][0]), min(red[2][0], red[3][0]));
  k1 = max(max(red[0][1], red[1][1]), max(red[2][1], red[3][1]));
  m0 = min(min(red[0][2], red[1][2]), min(red[2][2], red[3][2]));
  m1 = max(max(red[0][3], red[1][3]), max(red[2][3], red[3][3]));
  // 8-aligned ranges (extra taps are exact zeros -> bit-exact)
  const int A0 = __builtin_amdgcn_readfirstlane(k0 & ~7);
  const int A1 = __builtin_amdgcn_readfirstlane((k1 + 7) & ~7);
  const int B0 = __builtin_amdgcn_readfirstlane(m0 & ~7);
  const int B1 = __builtin_amdgcn_readfirstlane((m1 + 7) & ~7);
  const int U0 = min(A0, B0);
  const int U1 = max(A1, B1);

  const int bA = 4 * tid;           // group A outputs [bA, bA+4)
  const int bB = 1024 + 4 * tid;    // group B outputs [bB, bB+4)
  float acc1A[4], acc1B[4], acc2A[4], acc2B[4];
#pragma unroll
  for (int r = 0; r < 4; ++r) { acc1A[r] = 0.f; acc1B[r] = 0.f; acc2A[r] = 0.f; acc2B[r] = 0.f; }
  if (U0 < U1) {
    // rolling window: a0..a2 cover w[bA+k .. bA+k+12)
    float4 a0 = *(const float4*)&w[bA + U0];
    float4 a1 = *(const float4*)&w[bA + U0 + 4];
    float4 a2 = *(const float4*)&w[bA + U0 + 8];
    float4 b0 = *(const float4*)&w[bB + U0];
    float4 b1 = *(const float4*)&w[bB + U0 + 4];
    float4 b2 = *(const float4*)&w[bB + U0 + 8];
    float4 h1a = *(const float4*)&hs1[U0];
    float4 h1b = *(const float4*)&hs1[U0 + 4];
    float4 h2a = *(const float4*)&hs2[U0];
    float4 h2b = *(const float4*)&hs2[U0 + 4];
    for (int k = U0; k < U1; k += 8) {
      // prefetch next iteration (max index exactly fits arrays)
      float4 a3 = *(const float4*)&w[bA + k + 12];
      float4 a4 = *(const float4*)&w[bA + k + 16];
      float4 b3 = *(const float4*)&w[bB + k + 12];
      float4 b4 = *(const float4*)&w[bB + k + 16];
      float4 h1an = *(const float4*)&hs1[k + 8];
      float4 h1bn = *(const float4*)&hs1[k + 12];
      float4 h2an = *(const float4*)&hs2[k + 8];
      float4 h2bn = *(const float4*)&hs2[k + 12];
      float wa[11] = {a0.x, a0.y, a0.z, a0.w, a1.x, a1.y, a1.z, a1.w,
                      a2.x, a2.y, a2.z};
      float wb[11] = {b0.x, b0.y, b0.z, b0.w, b1.x, b1.y, b1.z, b1.w,
                      b2.x, b2.y, b2.z};
      float h1[8] = {h1a.x, h1a.y, h1a.z, h1a.w, h1b.x, h1b.y, h1b.z, h1b.w};
      float h2[8] = {h2a.x, h2a.y, h2a.z, h2a.w, h2b.x, h2b.y, h2b.z, h2b.w};
      if (k >= A0 && k < A1) {
#pragma unroll
        for (int r = 0; r < 4; ++r) {
#pragma unroll
          for (int j = 0; j < 8; ++j) {
            acc1A[r] = fmaf(h1[j], wa[r + j], acc1A[r]);
            acc1B[r] = fmaf(h1[j], wb[r + j], acc1B[r]);
          }
        }
      }
      if (k >= B0 && k < B1) {
#pragma unroll
        for (int r = 0; r < 4; ++r) {
#pragma unroll
          for (int j = 0; j < 8; ++j) {
            acc2A[r] = fmaf(h2[j], wa[r + j], acc2A[r]);
            acc2B[r] = fmaf(h2[j], wb[r + j], acc2B[r]);
          }
        }
      }
      a0 = a2; a1 = a3; a2 = a4;
      b0 = b2; b1 = b3; b2 = b4;
      h1a = h1an; h1b = h1bn;
      h2a = h2an; h2b = h2bn;
    }
  }
  float* out1 = filt + ((size_t)n * NF + o1) * TT;
  float* out2 = filt + ((size_t)n * NF + o2) * TT;
  *(float4*)&out1[bA] = make_float4(acc1A[0], acc1A[1], acc1A[2], acc1A[3]);
  *(float4*)&out1[bB] = make_float4(acc1B[0], acc1B[1], acc1B[2], acc1B[3]);
  *(float4*)&out2[bA] = make_float4(acc2A[0], acc2A[1], acc2A[2], acc2A[3]);
  *(float4*)&out2[bB] = make_float4(acc2B[0], acc2B[1], acc2B[2], acc2B[3]);
}

// ---------------------------------------------------------------------------
// Kernel B: Hilbert for TWO real rows per block via one complex FFT.
//   w = IFFT(mask * FFT(x1 + i*x2)) = z1 + i*z2  (mask is linear)
//   Re(z)=x exactly  =>  h1 = Im(w) - x2,  h2 = x1 - Re(w)
// Forward DIF + inverse DIT, Hilbert mask applied in bit-reversed space
// (pure parity rule) -> no bit-reversal pass (was a 64-way bank conflict).
// ---------------------------------------------------------------------------
__global__ __launch_bounds__(256) void hilbert_kernel(float* __restrict__ filt) {
  __shared__ float re[TT], im[TT];
  __shared__ float twr[TT], twi[TT];   // tw[half+j] = exp(-i*pi*j/half)
  const int tid = threadIdx.x;
  const int blk = blockIdx.x;          // rows 2*blk, 2*blk+1
  float* row1 = filt + (size_t)(2 * blk) * TT;
  float* row2 = row1 + TT;
  for (int i = tid; i < TT; i += 256) {
    if (i == 0) { twr[0] = 1.f; twi[0] = 0.f; }
    else {
      int half = 1 << (31 - __clz(i));
      int j = i - half;
      float ang = -3.14159265358979323846f * (float)j / (float)half;
      float s, c;
      sincosf(ang, &s, &c);
      twr[i] = c; twi[i] = s;
    }
    re[i] = row1[i];
    im[i] = row2[i];
  }
  __syncthreads();
  // ---- forward DIF: half = 1024 .. 1, output in bit-reversed order ----
  for (int half = 1024; half >= 1; half >>= 1) {
    for (int bf = tid; bf < 1024; bf += 256) {
      const int j = bf & (half - 1);
      const int i0 = ((bf & ~(half - 1)) << 1) + j;
      const int i1 = i0 + half;
      const float c = twr[half + j], s = twi[half + j];
      float ur = re[i0], ui = im[i0];
      float vr = re[i1], vi = im[i1];
      re[i0] = ur + vr; im[i0] = ui + vi;
      float dr = ur - vr, di = ui - vi;
      re[i1] = fmaf(c, dr, -(s * di));
      im[i1] = fmaf(c, di, s * dr);
    }
    __syncthreads();
  }
  // ---- Hilbert mask in bit-reversed space ----
  for (int jj = tid; jj < TT; jj += 256) {
    if (jj >= 2) {
      if (jj & 1) { re[jj] = 0.f; im[jj] = 0.f; }
      else        { re[jj] *= 2.f; im[jj] *= 2.f; }
    }
  }
  __syncthreads();
  // ---- inverse DIT: half = 1 .. 1024, bit-reversed in -> natural out ----
  for (int half = 1; half <= 1024; half <<= 1) {
    for (int bf = tid; bf < 1024; bf += 256) {
      const int j = bf & (half - 1);
      const int i0 = ((bf & ~(half - 1)) << 1) + j;
      const int i1 = i0 + half;
      const float c = twr[half + j], s = twi[half + j];  // use conj -> e^{+i}
      float vr = re[i1], vi = im[i1];
      float tr = fmaf(c, vr, s * vi);
      float ti = fmaf(c, vi, -(s * vr));
      float ur = re[i0], ui = im[i0];
      re[i0] = ur + tr; im[i0] = ui + ti;
      re[i1] = ur - tr; im[i1] = ui - ti;
    }
    __syncthreads();
  }
  // ---- recover h1,h2; write phase/amp ----
  const int o1 = (2 * blk) % NF;       // even -> pair never crosses pha/amp
  const bool p1 = o1 < 10, p2 = (o1 + 1) < 10;
  const float invN = 1.0f / 2048.0f;
  for (int t = tid; t < TT; t += 256) {
    float x1 = row1[t], x2 = row2[t];
    float wr = re[t] * invN, wi = im[t] * invN;
    float h1 = wi - x2;
    float h2 = x1 - wr;
    row1[t] = p1 ? atan2f(h1, x1) : sqrtf(fmaf(x1, x1, h1 * h1));
    row2[t] = p2 ? atan2f(h2, x2) : sqrtf(fmaf(x2, x2, h2 * h2));
  }
}

// ---------------------------------------------------------------------------
// Kernel C: binned MI, dense register accumulation v3.
// R9: chunked software pipeline - 4 chunks x 4 (float4 amp + int4 idx);
// chunk c+1's 8 loads issue before chunk c's ~1760-cycle body, so only the
// first chunk pays the ~200-cycle L2 latency (R8 paid it ~16x).
// Counts computed in the idx phase. Scrambled (reshape) pairing, round-2.
// ---------------------------------------------------------------------------
__global__ __launch_bounds__(320) void mi_kernel(const float* __restrict__ filt,
                                                 float* __restrict__ mi) {
  __shared__ __align__(16) int idx[TT];
  __shared__ float asum[10 * 19];
  __shared__ int cred[5 * 18];
  __shared__ float csum[18];
  const int tid = threadIdx.x;
  const int blk = blockIdx.x;           // bc*40 + jp
  const int bc = blk / 40, jp = blk % 40;
  const float* ph = filt + ((size_t)(bc * 4 + jp / 10) * NF + (jp % 10)) * TT;
  // ---- phase 1: bin indices + counts (phase-row only) ----
  int myc[18];
#pragma unroll
  for (int b = 0; b < 18; ++b) myc[b] = 0;
  for (int t = tid; t < TT; t += 320) {
    float v = ph[t];
    int b = (int)floorf((v + 3.14159274f) / 6.2831855f * 18.0f);
    b = b < 0 ? 0 : (b > 17 ? 17 : b);
    idx[t] = b;
#pragma unroll
    for (int b0 = 0; b0 < 18; ++b0) myc[b0] += (b == b0) ? 1 : 0;
  }
#pragma unroll
  for (int b = 0; b < 18; ++b) {
#pragma unroll
    for (int off = 32; off > 0; off >>= 1)
      myc[b] += __shfl_xor(myc[b], off);
  }
  if ((tid & 63) == 0) {
    const int wv = tid >> 6;
#pragma unroll
    for (int b = 0; b < 18; ++b) cred[wv * 18 + b] = myc[b];
  }
  __syncthreads();
  if (tid < 18) {
    int s = 0;
#pragma unroll
    for (int wv = 0; wv < 5; ++wv) s += cred[wv * 18 + tid];
    csum[tid] = (float)s;
  }
  // ---- phase 2: dense amp-sum, pipelined float4/int4 chunks ----
  const int a = tid >> 5, sl = tid & 31;   // a = a' (output amp index)
  const int ja = (jp & 3) + 4 * a;         // scrambled amp row, same s'
  const float* am = filt + ((size_t)(bc * 4 + ja / 10) * NF + 10 + (ja % 10)) * TT;
  float acc[18];
#pragma unroll
  for (int b = 0; b < 18; ++b) acc[b] = 0.f;
  float4 av[4], avn[4];
  int4 bx[4], bxn[4];
#pragma unroll
  for (int j = 0; j < 4; ++j) {
    const int base = j * 128 + sl * 4;     // 32 lanes x 16B contiguous
    av[j] = *(const float4*)&am[base];
    bx[j] = *(const int4*)&idx[base];
  }
  for (int c = 0; c < 4; ++c) {
    if (c < 3) {
#pragma unroll
      for (int j = 0; j < 4; ++j) {
        const int base = (c + 1) * 512 + j * 128 + sl * 4;
        avn[j] = *(const float4*)&am[base];
        bxn[j] = *(const int4*)&idx[base];
      }
    }
#pragma unroll
    for (int j = 0; j < 4; ++j) {
#pragma unroll
      for (int b0 = 0; b0 < 18; ++b0) {
        acc[b0] += (bx[j].x == b0) ? av[j].x : 0.f;
        acc[b0] += (bx[j].y == b0) ? av[j].y : 0.f;
        acc[b0] += (bx[j].z == b0) ? av[j].z : 0.f;
        acc[b0] += (bx[j].w == b0) ? av[j].w : 0.f;
      }
    }
#pragma unroll
    for (int j = 0; j < 4; ++j) { av[j] = avn[j]; bx[j] = bxn[j]; }
  }
  // butterfly over the 32-lane half-wave (xor offsets stay within half)
#pragma unroll
  for (int b = 0; b < 18; ++b) {
#pragma unroll
    for (int off = 16; off > 0; off >>= 1)
      acc[b] += __shfl_xor(acc[b], off);
  }
  if (sl == 0) {
#pragma unroll
    for (int b = 0; b < 18; ++b) asum[a * 19 + b] = acc[b];
  }
  __syncthreads();
  // ---- phase 3: MI ----
  if (tid < 10) {
    float tot = 0.f, m[18];
#pragma unroll
    for (int b = 0; b < 18; ++b) {
      float mb = asum[tid * 19 + b] / fmaxf(csum[b], 1.0f);
      m[b] = mb; tot += mb;
    }
    tot = fmaxf(tot, 1e-12f);
    float s = 0.f;
#pragma unroll
    for (int b = 0; b < 18; ++b) {
      float pb = m[b] / tot;
      s += pb * logf(fmaxf(pb, 1e-12f));
    }
    const float LOGN = 2.8903717578961645f; // log(18)
    mi[(size_t)blk * 10 + tid] = (LOGN + s) / LOGN;
  }
}

// ---------------------------------------------------------------------------
// Kernel D: mean over the scrambled s' axis -> out (4,8,10,10)
// ---------------------------------------------------------------------------
__global__ void out_kernel(const float* __restrict__ mi, float* __restrict__ out) {
  int i = blockIdx.x * 256 + threadIdx.x;
  if (i < 3200) {
    int a = i % 10, p = (i / 10) % 10, bc = i / 100;
    float s = 0.f;
    for (int sp = 0; sp < 4; ++sp)
      s += mi[((size_t)(bc * 40 + p * 4 + sp)) * 10 + a];
    out[i] = 0.25f * s;
  }
}

extern "C" void kernel_launch(void* const* d_in, const int* in_sizes, int n_in,
                              void* d_out, int out_size, void* d_ws, size_t ws_size,
                              hipStream_t stream) {
  (void)in_sizes; (void)n_in; (void)out_size; (void)ws_size;
  const float* x = (const float*)d_in[0];     // (4,8,4,2048) fp32
  const float* ker = (const float*)d_in[1];   // (20,769) fp32
  float* out = (float*)d_out;                 // 3200 fp32
  float* filt = (float*)d_ws;                 // 128*20*2048 fp32 (~21 MB)
  float* mi = filt + (size_t)NS * NF * TT;    // 12800 fp32

  conv_kernel<<<NS * 10, 256, 0, stream>>>(x, ker, filt);
  hilbert_kernel<<<NS * NF / 2, 256, 0, stream>>>(filt);
  mi_kernel<<<32 * 40, 320, 0, stream>>>(filt, mi);
  out_kernel<<<(3200 + 255) / 256, 256, 0, stream>>>(mi, out);
}

// Round 10
// 185.686 us; speedup vs baseline: 1.0904x; 1.0904x over previous
//
#include <hip/hip_runtime.h>
#include <math.h>

#define TT 2048
#define LK 769
#define NF 20
#define NS 128
#define NB 18

// ---------------------------------------------------------------------------
// Kernel A: symmetric FIR conv (fwd+bwd averaged == conv with symmetrized
// taps), reflect padding folded into index mirror.
// One wg per (signal, filter-PAIR): pha band p + amp band (9-p) share the
// same LDS signal window. 8 taps/iter with a 3-register float4 rolling
// window and explicit next-iteration prefetch of taps+window. Tap order
// per output unchanged (extra range-rounding taps are exact zeros).
// ---------------------------------------------------------------------------
__global__ __launch_bounds__(256) void conv_kernel(const float* __restrict__ x,
                                                   const float* __restrict__ ker,
                                                   float* __restrict__ filt) {
  __shared__ __align__(16) float w[2832];   // spad[384..3200) + zero tail
  __shared__ __align__(16) float hs1[784];  // symmetrized pha filter
  __shared__ __align__(16) float hs2[784];  // symmetrized amp filter
  __shared__ int red[4][4];
  const int tid = threadIdx.x;
  const int ord = blockIdx.x;
  const int p = ord / NS;                   // 0..9, longest pair first
  const int n = ord % NS;
  const int o1 = p;                          // pha band
  const int o2 = 10 + (9 - p);               // amp band (short with long)
  const float* xr = x + n * TT;
  for (int j = tid; j < 2832; j += 256) {
    float v = 0.f;
    if (j < 2816) {
      int m = j - 384;              // spad[j+384] -> original index (j+384)-768
      if (m < 0) m = -m;            // reflect (edge excluded)
      if (m > 2047) m = 4094 - m;
      v = xr[m];
    }
    w[j] = v;
  }
  const float* kr1 = ker + o1 * LK;
  const float* kr2 = ker + o2 * LK;
  int k0 = 784, k1 = 0, m0 = 784, m1 = 0;
  for (int k = tid; k < 784; k += 256) {
    float v1 = 0.f, v2 = 0.f;
    if (k < LK) {
      v1 = 0.5f * (kr1[k] + kr1[LK - 1 - k]);
      v2 = 0.5f * (kr2[k] + kr2[LK - 1 - k]);
    }
    hs1[k] = v1;
    hs2[k] = v2;
    if (v1 != 0.f) { k0 = min(k0, k); k1 = max(k1, k + 1); }
    if (v2 != 0.f) { m0 = min(m0, k); m1 = max(m1, k + 1); }
  }
#pragma unroll
  for (int off = 32; off > 0; off >>= 1) {
    k0 = min(k0, __shfl_down(k0, off));
    k1 = max(k1, __shfl_down(k1, off));
    m0 = min(m0, __shfl_down(m0, off));
    m1 = max(m1, __shfl_down(m1, off));
  }
  const int wid = tid >> 6;
  if ((tid & 63) == 0) { red[wid][0] = k0; red[wid][1] = k1; red[wid][2] = m0; red[wid][3] = m1; }
  __syncthreads();
  k0 = min(min(red[0][0], red[1][0]), min(red[2][0], red[3][0]));
  k1 = max(max(red[0][1], red[1][1]), max(red[2][1], red[3][1]));
  m0 = min(min(red[0][2], red[1][2]), min(red[2][2], red[3][2]));
  m1 = max(max(red[0][3], red[1][3]), max(red[2][3], red[3][3]));
  // 8-aligned ranges (extra taps are exact zeros -> bit-exact)
  const int A0 = __builtin_amdgcn_readfirstlane(k0 & ~7);
  const int A1 = __builtin_amdgcn_readfirstlane((k1 + 7) & ~7);
  const int B0 = __builtin_amdgcn_readfirstlane(m0 & ~7);
  const int B1 = __builtin_amdgcn_readfirstlane((m1 + 7) & ~7);
  const int U0 = min(A0, B0);
  const int U1 = max(A1, B1);

  const int bA = 4 * tid;           // group A outputs [bA, bA+4)
  const int bB = 1024 + 4 * tid;    // group B outputs [bB, bB+4)
  float acc1A[4], acc1B[4], acc2A[4], acc2B[4];
#pragma unroll
  for (int r = 0; r < 4; ++r) { acc1A[r] = 0.f; acc1B[r] = 0.f; acc2A[r] = 0.f; acc2B[r] = 0.f; }
  if (U0 < U1) {
    // rolling window: a0..a2 cover w[bA+k .. bA+k+12)
    float4 a0 = *(const float4*)&w[bA + U0];
    float4 a1 = *(const float4*)&w[bA + U0 + 4];
    float4 a2 = *(const float4*)&w[bA + U0 + 8];
    float4 b0 = *(const float4*)&w[bB + U0];
    float4 b1 = *(const float4*)&w[bB + U0 + 4];
    float4 b2 = *(const float4*)&w[bB + U0 + 8];
    float4 h1a = *(const float4*)&hs1[U0];
    float4 h1b = *(const float4*)&hs1[U0 + 4];
    float4 h2a = *(const float4*)&hs2[U0];
    float4 h2b = *(const float4*)&hs2[U0 + 4];
    for (int k = U0; k < U1; k += 8) {
      // prefetch next iteration (max index exactly fits arrays)
      float4 a3 = *(const float4*)&w[bA + k + 12];
      float4 a4 = *(const float4*)&w[bA + k + 16];
      float4 b3 = *(const float4*)&w[bB + k + 12];
      float4 b4 = *(const float4*)&w[bB + k + 16];
      float4 h1an = *(const float4*)&hs1[k + 8];
      float4 h1bn = *(const float4*)&hs1[k + 12];
      float4 h2an = *(const float4*)&hs2[k + 8];
      float4 h2bn = *(const float4*)&hs2[k + 12];
      float wa[11] = {a0.x, a0.y, a0.z, a0.w, a1.x, a1.y, a1.z, a1.w,
                      a2.x, a2.y, a2.z};
      float wb[11] = {b0.x, b0.y, b0.z, b0.w, b1.x, b1.y, b1.z, b1.w,
                      b2.x, b2.y, b2.z};
      float h1[8] = {h1a.x, h1a.y, h1a.z, h1a.w, h1b.x, h1b.y, h1b.z, h1b.w};
      float h2[8] = {h2a.x, h2a.y, h2a.z, h2a.w, h2b.x, h2b.y, h2b.z, h2b.w};
      if (k >= A0 && k < A1) {
#pragma unroll
        for (int r = 0; r < 4; ++r) {
#pragma unroll
          for (int j = 0; j < 8; ++j) {
            acc1A[r] = fmaf(h1[j], wa[r + j], acc1A[r]);
            acc1B[r] = fmaf(h1[j], wb[r + j], acc1B[r]);
          }
        }
      }
      if (k >= B0 && k < B1) {
#pragma unroll
        for (int r = 0; r < 4; ++r) {
#pragma unroll
          for (int j = 0; j < 8; ++j) {
            acc2A[r] = fmaf(h2[j], wa[r + j], acc2A[r]);
            acc2B[r] = fmaf(h2[j], wb[r + j], acc2B[r]);
          }
        }
      }
      a0 = a2; a1 = a3; a2 = a4;
      b0 = b2; b1 = b3; b2 = b4;
      h1a = h1an; h1b = h1bn;
      h2a = h2an; h2b = h2bn;
    }
  }
  float* out1 = filt + ((size_t)n * NF + o1) * TT;
  float* out2 = filt + ((size_t)n * NF + o2) * TT;
  *(float4*)&out1[bA] = make_float4(acc1A[0], acc1A[1], acc1A[2], acc1A[3]);
  *(float4*)&out1[bB] = make_float4(acc1B[0], acc1B[1], acc1B[2], acc1B[3]);
  *(float4*)&out2[bA] = make_float4(acc2A[0], acc2A[1], acc2A[2], acc2A[3]);
  *(float4*)&out2[bB] = make_float4(acc2B[0], acc2B[1], acc2B[2], acc2B[3]);
}

// ---------------------------------------------------------------------------
// Kernel B: Hilbert for TWO real rows per block via one complex FFT.
//   w = IFFT(mask * FFT(x1 + i*x2)) = z1 + i*z2  (mask is linear)
//   Re(z)=x exactly  =>  h1 = Im(w) - x2,  h2 = x1 - Re(w)
// Forward DIF + inverse DIT, Hilbert mask applied in bit-reversed space
// (pure parity rule) -> no bit-reversal pass.
// R10: complex interleaved as float2 -> every butterfly is ds_read_b64/
// ds_write_b64 (half the DS instructions; the kernel is DS-throughput
// bound). Stride-8B large stages = 2-way conflict = free (m136).
// Arithmetic order identical to R9.
// ---------------------------------------------------------------------------
__global__ __launch_bounds__(256) void hilbert_kernel(float* __restrict__ filt) {
  __shared__ __align__(16) float2 z[TT];
  __shared__ __align__(16) float2 tw[TT];  // tw[half+j] = exp(-i*pi*j/half)
  const int tid = threadIdx.x;
  const int blk = blockIdx.x;          // rows 2*blk, 2*blk+1
  float* row1 = filt + (size_t)(2 * blk) * TT;
  float* row2 = row1 + TT;
  for (int i = tid; i < TT; i += 256) {
    if (i == 0) { tw[0] = make_float2(1.f, 0.f); }
    else {
      int half = 1 << (31 - __clz(i));
      int j = i - half;
      float ang = -3.14159265358979323846f * (float)j / (float)half;
      float s, c;
      sincosf(ang, &s, &c);
      tw[i] = make_float2(c, s);
    }
    z[i] = make_float2(row1[i], row2[i]);
  }
  __syncthreads();
  // ---- forward DIF: half = 1024 .. 1, output in bit-reversed order ----
  for (int half = 1024; half >= 1; half >>= 1) {
    for (int bf = tid; bf < 1024; bf += 256) {
      const int j = bf & (half - 1);
      const int i0 = ((bf & ~(half - 1)) << 1) + j;
      const int i1 = i0 + half;
      const float2 t = tw[half + j];
      const float2 u = z[i0];
      const float2 v = z[i1];
      z[i0] = make_float2(u.x + v.x, u.y + v.y);
      const float dr = u.x - v.x, di = u.y - v.y;
      z[i1] = make_float2(fmaf(t.x, dr, -(t.y * di)),
                          fmaf(t.x, di, t.y * dr));
    }
    __syncthreads();
  }
  // ---- Hilbert mask in bit-reversed space ----
  for (int jj = tid; jj < TT; jj += 256) {
    if (jj >= 2) {
      if (jj & 1) { z[jj] = make_float2(0.f, 0.f); }
      else        { float2 v = z[jj]; z[jj] = make_float2(2.f * v.x, 2.f * v.y); }
    }
  }
  __syncthreads();
  // ---- inverse DIT: half = 1 .. 1024, bit-reversed in -> natural out ----
  for (int half = 1; half <= 1024; half <<= 1) {
    for (int bf = tid; bf < 1024; bf += 256) {
      const int j = bf & (half - 1);
      const int i0 = ((bf & ~(half - 1)) << 1) + j;
      const int i1 = i0 + half;
      const float2 t = tw[half + j];           // conj -> e^{+i}
      const float2 v = z[i1];
      const float tr = fmaf(t.x, v.x, t.y * v.y);
      const float ti = fmaf(t.x, v.y, -(t.y * v.x));
      const float2 u = z[i0];
      z[i0] = make_float2(u.x + tr, u.y + ti);
      z[i1] = make_float2(u.x - tr, u.y - ti);
    }
    __syncthreads();
  }
  // ---- recover h1,h2; write phase/amp ----
  const int o1 = (2 * blk) % NF;       // even -> pair never crosses pha/amp
  const bool p1 = o1 < 10, p2 = (o1 + 1) < 10;
  const float invN = 1.0f / 2048.0f;
  for (int t = tid; t < TT; t += 256) {
    float x1 = row1[t], x2 = row2[t];
    float2 wv = z[t];
    float wr = wv.x * invN, wi = wv.y * invN;
    float h1 = wi - x2;
    float h2 = x1 - wr;
    row1[t] = p1 ? atan2f(h1, x1) : sqrtf(fmaf(x1, x1, h1 * h1));
    row2[t] = p2 ? atan2f(h2, x2) : sqrtf(fmaf(x2, x2, h2 * h2));
  }
}

// ---------------------------------------------------------------------------
// Kernel C: binned MI, dense register accumulation (R8 version — reverted
// from R9's deep pipeline, which doubled VGPR to 60 and halved occupancy).
// Counts computed in the idx phase (dense per-thread ints, butterfly
// reduced); float4 amp + int4 idx inner loop (unroll 4).
// Scrambled (reshape) pairing as per round-2 notes.
// ---------------------------------------------------------------------------
__global__ __launch_bounds__(320) void mi_kernel(const float* __restrict__ filt,
                                                 float* __restrict__ mi) {
  __shared__ __align__(16) int idx[TT];
  __shared__ float asum[10 * 19];
  __shared__ int cred[5 * 18];
  __shared__ float csum[18];
  const int tid = threadIdx.x;
  const int blk = blockIdx.x;           // bc*40 + jp
  const int bc = blk / 40, jp = blk % 40;
  const float* ph = filt + ((size_t)(bc * 4 + jp / 10) * NF + (jp % 10)) * TT;
  // ---- phase 1: bin indices + counts (phase-row only) ----
  int myc[18];
#pragma unroll
  for (int b = 0; b < 18; ++b) myc[b] = 0;
  for (int t = tid; t < TT; t += 320) {
    float v = ph[t];
    int b = (int)floorf((v + 3.14159274f) / 6.2831855f * 18.0f);
    b = b < 0 ? 0 : (b > 17 ? 17 : b);
    idx[t] = b;
#pragma unroll
    for (int b0 = 0; b0 < 18; ++b0) myc[b0] += (b == b0) ? 1 : 0;
  }
#pragma unroll
  for (int b = 0; b < 18; ++b) {
#pragma unroll
    for (int off = 32; off > 0; off >>= 1)
      myc[b] += __shfl_xor(myc[b], off);
  }
  if ((tid & 63) == 0) {
    const int wv = tid >> 6;
#pragma unroll
    for (int b = 0; b < 18; ++b) cred[wv * 18 + b] = myc[b];
  }
  __syncthreads();
  if (tid < 18) {
    int s = 0;
#pragma unroll
    for (int wv = 0; wv < 5; ++wv) s += cred[wv * 18 + tid];
    csum[tid] = (float)s;
  }
  // ---- phase 2: dense amp-sum, float4/int4 inner ----
  const int a = tid >> 5, sl = tid & 31;   // a = a' (output amp index)
  const int ja = (jp & 3) + 4 * a;         // scrambled amp row, same s'
  const float* am = filt + ((size_t)(bc * 4 + ja / 10) * NF + 10 + (ja % 10)) * TT;
  float acc[18];
#pragma unroll
  for (int b = 0; b < 18; ++b) acc[b] = 0.f;
#pragma unroll 4
  for (int k = 0; k < 16; ++k) {
    const int base = k * 128 + sl * 4;     // 32 lanes x 16B contiguous
    const float4 av = *(const float4*)&am[base];
    const int4 bx = *(const int4*)&idx[base];
#pragma unroll
    for (int b0 = 0; b0 < 18; ++b0) {
      acc[b0] += (bx.x == b0) ? av.x : 0.f;
      acc[b0] += (bx.y == b0) ? av.y : 0.f;
      acc[b0] += (bx.z == b0) ? av.z : 0.f;
      acc[b0] += (bx.w == b0) ? av.w : 0.f;
    }
  }
  // butterfly over the 32-lane half-wave (xor offsets stay within half)
#pragma unroll
  for (int b = 0; b < 18; ++b) {
#pragma unroll
    for (int off = 16; off > 0; off >>= 1)
      acc[b] += __shfl_xor(acc[b], off);
  }
  if (sl == 0) {
#pragma unroll
    for (int b = 0; b < 18; ++b) asum[a * 19 + b] = acc[b];
  }
  __syncthreads();
  // ---- phase 3: MI ----
  if (tid < 10) {
    float tot = 0.f, m[18];
#pragma unroll
    for (int b = 0; b < 18; ++b) {
      float mb = asum[tid * 19 + b] / fmaxf(csum[b], 1.0f);
      m[b] = mb; tot += mb;
    }
    tot = fmaxf(tot, 1e-12f);
    float s = 0.f;
#pragma unroll
    for (int b = 0; b < 18; ++b) {
      float pb = m[b] / tot;
      s += pb * logf(fmaxf(pb, 1e-12f));
    }
    const float LOGN = 2.8903717578961645f; // log(18)
    mi[(size_t)blk * 10 + tid] = (LOGN + s) / LOGN;
  }
}

// ---------------------------------------------------------------------------
// Kernel D: mean over the scrambled s' axis -> out (4,8,10,10)
// ---------------------------------------------------------------------------
__global__ void out_kernel(const float* __restrict__ mi, float* __restrict__ out) {
  int i = blockIdx.x * 256 + threadIdx.x;
  if (i < 3200) {
    int a = i % 10, p = (i / 10) % 10, bc = i / 100;
    float s = 0.f;
    for (int sp = 0; sp < 4; ++sp)
      s += mi[((size_t)(bc * 40 + p * 4 + sp)) * 10 + a];
    out[i] = 0.25f * s;
  }
}

extern "C" void kernel_launch(void* const* d_in, const int* in_sizes, int n_in,
                              void* d_out, int out_size, void* d_ws, size_t ws_size,
                              hipStream_t stream) {
  (void)in_sizes; (void)n_in; (void)out_size; (void)ws_size;
  const float* x = (const float*)d_in[0];     // (4,8,4,2048) fp32
  const float* ker = (const float*)d_in[1];   // (20,769) fp32
  float* out = (float*)d_out;                 // 3200 fp32
  float* filt = (float*)d_ws;                 // 128*20*2048 fp32 (~21 MB)
  float* mi = filt + (size_t)NS * NF * TT;    // 12800 fp32

  conv_kernel<<<NS * 10, 256, 0, stream>>>(x, ker, filt);
  hilbert_kernel<<<NS * NF / 2, 256, 0, stream>>>(filt);
  mi_kernel<<<32 * 40, 320, 0, stream>>>(filt, mi);
  out_kernel<<<(3200 + 255) / 256, 256, 0, stream>>>(mi, out);
}

// Round 12
// 170.038 us; speedup vs baseline: 1.1907x; 1.0920x over previous
//
#include <hip/hip_runtime.h>
#include <math.h>

#define TT 2048
#define LK 769
#define NF 20
#define NS 128
#define NB 18

typedef __attribute__((ext_vector_type(8))) short short8;
typedef __attribute__((ext_vector_type(4))) float f32x4;

// ---------------------------------------------------------------------------
// Kernel A: symmetric FIR conv (unchanged from R10).
// ---------------------------------------------------------------------------
__global__ __launch_bounds__(256) void conv_kernel(const float* __restrict__ x,
                                                   const float* __restrict__ ker,
                                                   float* __restrict__ filt) {
  __shared__ __align__(16) float w[2832];   // spad[384..3200) + zero tail
  __shared__ __align__(16) float hs1[784];  // symmetrized pha filter
  __shared__ __align__(16) float hs2[784];  // symmetrized amp filter
  __shared__ int red[4][4];
  const int tid = threadIdx.x;
  const int ord = blockIdx.x;
  const int p = ord / NS;                   // 0..9, longest pair first
  const int n = ord % NS;
  const int o1 = p;                          // pha band
  const int o2 = 10 + (9 - p);               // amp band (short with long)
  const float* xr = x + n * TT;
  for (int j = tid; j < 2832; j += 256) {
    float v = 0.f;
    if (j < 2816) {
      int m = j - 384;              // spad[j+384] -> original index (j+384)-768
      if (m < 0) m = -m;            // reflect (edge excluded)
      if (m > 2047) m = 4094 - m;
      v = xr[m];
    }
    w[j] = v;
  }
  const float* kr1 = ker + o1 * LK;
  const float* kr2 = ker + o2 * LK;
  int k0 = 784, k1 = 0, m0 = 784, m1 = 0;
  for (int k = tid; k < 784; k += 256) {
    float v1 = 0.f, v2 = 0.f;
    if (k < LK) {
      v1 = 0.5f * (kr1[k] + kr1[LK - 1 - k]);
      v2 = 0.5f * (kr2[k] + kr2[LK - 1 - k]);
    }
    hs1[k] = v1;
    hs2[k] = v2;
    if (v1 != 0.f) { k0 = min(k0, k); k1 = max(k1, k + 1); }
    if (v2 != 0.f) { m0 = min(m0, k); m1 = max(m1, k + 1); }
  }
#pragma unroll
  for (int off = 32; off > 0; off >>= 1) {
    k0 = min(k0, __shfl_down(k0, off));
    k1 = max(k1, __shfl_down(k1, off));
    m0 = min(m0, __shfl_down(m0, off));
    m1 = max(m1, __shfl_down(m1, off));
  }
  const int wid = tid >> 6;
  if ((tid & 63) == 0) { red[wid][0] = k0; red[wid][1] = k1; red[wid][2] = m0; red[wid][3] = m1; }
  __syncthreads();
  k0 = min(min(red[0][0], red[1][0]), min(red[2][0], red[3][0]));
  k1 = max(max(red[0][1], red[1][1]), max(red[2][1], red[3][1]));
  m0 = min(min(red[0][2], red[1][2]), min(red[2][2], red[3][2]));
  m1 = max(max(red[0][3], red[1][3]), max(red[2][3], red[3][3]));
  // 8-aligned ranges (extra taps are exact zeros -> bit-exact)
  const int A0 = __builtin_amdgcn_readfirstlane(k0 & ~7);
  const int A1 = __builtin_amdgcn_readfirstlane((k1 + 7) & ~7);
  const int B0 = __builtin_amdgcn_readfirstlane(m0 & ~7);
  const int B1 = __builtin_amdgcn_readfirstlane((m1 + 7) & ~7);
  const int U0 = min(A0, B0);
  const int U1 = max(A1, B1);

  const int bA = 4 * tid;           // group A outputs [bA, bA+4)
  const int bB = 1024 + 4 * tid;    // group B outputs [bB, bB+4)
  float acc1A[4], acc1B[4], acc2A[4], acc2B[4];
#pragma unroll
  for (int r = 0; r < 4; ++r) { acc1A[r] = 0.f; acc1B[r] = 0.f; acc2A[r] = 0.f; acc2B[r] = 0.f; }
  if (U0 < U1) {
    // rolling window: a0..a2 cover w[bA+k .. bA+k+12)
    float4 a0 = *(const float4*)&w[bA + U0];
    float4 a1 = *(const float4*)&w[bA + U0 + 4];
    float4 a2 = *(const float4*)&w[bA + U0 + 8];
    float4 b0 = *(const float4*)&w[bB + U0];
    float4 b1 = *(const float4*)&w[bB + U0 + 4];
    float4 b2 = *(const float4*)&w[bB + U0 + 8];
    float4 h1a = *(const float4*)&hs1[U0];
    float4 h1b = *(const float4*)&hs1[U0 + 4];
    float4 h2a = *(const float4*)&hs2[U0];
    float4 h2b = *(const float4*)&hs2[U0 + 4];
    for (int k = U0; k < U1; k += 8) {
      float4 a3 = *(const float4*)&w[bA + k + 12];
      float4 a4 = *(const float4*)&w[bA + k + 16];
      float4 b3 = *(const float4*)&w[bB + k + 12];
      float4 b4 = *(const float4*)&w[bB + k + 16];
      float4 h1an = *(const float4*)&hs1[k + 8];
      float4 h1bn = *(const float4*)&hs1[k + 12];
      float4 h2an = *(const float4*)&hs2[k + 8];
      float4 h2bn = *(const float4*)&hs2[k + 12];
      float wa[11] = {a0.x, a0.y, a0.z, a0.w, a1.x, a1.y, a1.z, a1.w,
                      a2.x, a2.y, a2.z};
      float wb[11] = {b0.x, b0.y, b0.z, b0.w, b1.x, b1.y, b1.z, b1.w,
                      b2.x, b2.y, b2.z};
      float h1[8] = {h1a.x, h1a.y, h1a.z, h1a.w, h1b.x, h1b.y, h1b.z, h1b.w};
      float h2[8] = {h2a.x, h2a.y, h2a.z, h2a.w, h2b.x, h2b.y, h2b.z, h2b.w};
      if (k >= A0 && k < A1) {
#pragma unroll
        for (int r = 0; r < 4; ++r) {
#pragma unroll
          for (int j = 0; j < 8; ++j) {
            acc1A[r] = fmaf(h1[j], wa[r + j], acc1A[r]);
            acc1B[r] = fmaf(h1[j], wb[r + j], acc1B[r]);
          }
        }
      }
      if (k >= B0 && k < B1) {
#pragma unroll
        for (int r = 0; r < 4; ++r) {
#pragma unroll
          for (int j = 0; j < 8; ++j) {
            acc2A[r] = fmaf(h2[j], wa[r + j], acc2A[r]);
            acc2B[r] = fmaf(h2[j], wb[r + j], acc2B[r]);
          }
        }
      }
      a0 = a2; a1 = a3; a2 = a4;
      b0 = b2; b1 = b3; b2 = b4;
      h1a = h1an; h1b = h1bn;
      h2a = h2an; h2b = h2bn;
    }
  }
  float* out1 = filt + ((size_t)n * NF + o1) * TT;
  float* out2 = filt + ((size_t)n * NF + o2) * TT;
  *(float4*)&out1[bA] = make_float4(acc1A[0], acc1A[1], acc1A[2], acc1A[3]);
  *(float4*)&out1[bB] = make_float4(acc1B[0], acc1B[1], acc1B[2], acc1B[3]);
  *(float4*)&out2[bA] = make_float4(acc2A[0], acc2A[1], acc2A[2], acc2A[3]);
  *(float4*)&out2[bB] = make_float4(acc2B[0], acc2B[1], acc2B[2], acc2B[3]);
}

// ---------------------------------------------------------------------------
// Kernel B: Hilbert (unchanged from R10: float2-interleaved DIF/DIT, mask in
// bit-reversed space).
// ---------------------------------------------------------------------------
__global__ __launch_bounds__(256) void hilbert_kernel(float* __restrict__ filt) {
  __shared__ __align__(16) float2 z[TT];
  __shared__ __align__(16) float2 tw[TT];  // tw[half+j] = exp(-i*pi*j/half)
  const int tid = threadIdx.x;
  const int blk = blockIdx.x;          // rows 2*blk, 2*blk+1
  float* row1 = filt + (size_t)(2 * blk) * TT;
  float* row2 = row1 + TT;
  for (int i = tid; i < TT; i += 256) {
    if (i == 0) { tw[0] = make_float2(1.f, 0.f); }
    else {
      int half = 1 << (31 - __clz(i));
      int j = i - half;
      float ang = -3.14159265358979323846f * (float)j / (float)half;
      float s, c;
      sincosf(ang, &s, &c);
      tw[i] = make_float2(c, s);
    }
    z[i] = make_float2(row1[i], row2[i]);
  }
  __syncthreads();
  for (int half = 1024; half >= 1; half >>= 1) {
    for (int bf = tid; bf < 1024; bf += 256) {
      const int j = bf & (half - 1);
      const int i0 = ((bf & ~(half - 1)) << 1) + j;
      const int i1 = i0 + half;
      const float2 t = tw[half + j];
      const float2 u = z[i0];
      const float2 v = z[i1];
      z[i0] = make_float2(u.x + v.x, u.y + v.y);
      const float dr = u.x - v.x, di = u.y - v.y;
      z[i1] = make_float2(fmaf(t.x, dr, -(t.y * di)),
                          fmaf(t.x, di, t.y * dr));
    }
    __syncthreads();
  }
  for (int jj = tid; jj < TT; jj += 256) {
    if (jj >= 2) {
      if (jj & 1) { z[jj] = make_float2(0.f, 0.f); }
      else        { float2 v = z[jj]; z[jj] = make_float2(2.f * v.x, 2.f * v.y); }
    }
  }
  __syncthreads();
  for (int half = 1; half <= 1024; half <<= 1) {
    for (int bf = tid; bf < 1024; bf += 256) {
      const int j = bf & (half - 1);
      const int i0 = ((bf & ~(half - 1)) << 1) + j;
      const int i1 = i0 + half;
      const float2 t = tw[half + j];           // conj -> e^{+i}
      const float2 v = z[i1];
      const float tr = fmaf(t.x, v.x, t.y * v.y);
      const float ti = fmaf(t.x, v.y, -(t.y * v.x));
      const float2 u = z[i0];
      z[i0] = make_float2(u.x + tr, u.y + ti);
      z[i1] = make_float2(u.x - tr, u.y - ti);
    }
    __syncthreads();
  }
  const int o1 = (2 * blk) % NF;       // even -> pair never crosses pha/amp
  const bool p1 = o1 < 10, p2 = (o1 + 1) < 10;
  const float invN = 1.0f / 2048.0f;
  for (int t = tid; t < TT; t += 256) {
    float x1 = row1[t], x2 = row2[t];
    float2 wv = z[t];
    float wr = wv.x * invN, wi = wv.y * invN;
    float h1 = wi - x2;
    float h2 = x1 - wr;
    row1[t] = p1 ? atan2f(h1, x1) : sqrtf(fmaf(x1, x1, h1 * h1));
    row2[t] = p2 ? atan2f(h2, x2) : sqrtf(fmaf(x2, x2, h2 * h2));
  }
}

// ---------------------------------------------------------------------------
// Kernel C: binned MI via MFMA, v2 — VERIFIED 16x16x32 layouts (m89/m91):
//   A[m=lane&15][k=quad*8+j], B[k=quad*8+j][n=lane&15],
//   C: col=lane&15, row=quad*4+reg.
// amp_sum[a][b] = A(16x2048) x Onehot(2048x18): A rows 0-9 = scrambled amp
// (3-way exact bf16 split), row 10 = ones (counts free), rows 11-15 zero.
// N=16<18 -> two B one-hot groups (bins 0-15 / 16-17), two f32x4 accums.
// K-loop: 64 steps of K=32 (R11 bug: treated 32x32x16 as K=32 and skipped
// every odd 16-block of K — half the data never accumulated).
// One wave (64 thr) per (bc,jp). Scrambled (reshape) pairing per round-2.
// ---------------------------------------------------------------------------
__global__ __launch_bounds__(64) void mi_kernel(const float* __restrict__ filt,
                                                float* __restrict__ mi) {
  __shared__ __align__(16) unsigned int idx32[512];  // 4 bins/dword
  __shared__ float Cs[12][19];
  const int lane = threadIdx.x;
  const int blk = blockIdx.x;           // bc*40 + jp
  const int bc = blk / 40, jp = blk % 40;
  const float* ph = filt + ((size_t)(bc * 4 + jp / 10) * NF + (jp % 10)) * TT;
  // ---- phase 1: bin indices, packed 4 bytes/dword ----
  for (int g = lane; g < 512; g += 64) {
    float4 v = *(const float4*)&ph[4 * g];
    float vv[4] = {v.x, v.y, v.z, v.w};
    unsigned int packed = 0;
#pragma unroll
    for (int j = 0; j < 4; ++j) {
      int b = (int)floorf((vv[j] + 3.14159274f) / 6.2831855f * 18.0f);
      b = b < 0 ? 0 : (b > 17 ? 17 : b);
      packed |= ((unsigned int)b) << (8 * j);
    }
    idx32[g] = packed;
  }
  __syncthreads();
  // ---- phase 2: MFMA K-loop (64 steps x K=32) ----
  const int n16 = lane & 15;    // A row m / B col n / C col
  const int quad = lane >> 4;   // k-quad (0..3)
  const int aband = n16 < 10 ? n16 : 9;
  const int ja = (jp & 3) + 4 * aband;   // scrambled amp row, same s'
  const float* aptr = filt + ((size_t)(bc * 4 + ja / 10) * NF + 10 + (ja % 10)) * TT
                      + quad * 8;
  const bool isAmp = (n16 < 10);
  const bool isOne = (n16 == 10);
  f32x4 acc0 = {0.f, 0.f, 0.f, 0.f};     // bins 0..15
  f32x4 acc1 = {0.f, 0.f, 0.f, 0.f};     // bins 16..17 (cols 16+n16)
  float4 p0 = *(const float4*)(aptr);
  float4 p1 = *(const float4*)(aptr + 4);
  for (int s = 0; s < 64; ++s) {
    float4 c0 = p0, c1 = p1;
    if (s < 63) {
      p0 = *(const float4*)(aptr + (s + 1) * 32);
      p1 = *(const float4*)(aptr + (s + 1) * 32 + 4);
    }
    float a[8] = {c0.x, c0.y, c0.z, c0.w, c1.x, c1.y, c1.z, c1.w};
    short8 ah, am_, al;
#pragma unroll
    for (int j = 0; j < 8; ++j) {
      float v = isAmp ? a[j] : (isOne ? 1.0f : 0.0f);
      unsigned int u = __float_as_uint(v);
      float h = __uint_as_float(u & 0xFFFF0000u);
      float r1 = v - h;                       // exact (<=16 sig bits)
      unsigned int u2 = __float_as_uint(r1);
      float md = __uint_as_float(u2 & 0xFFFF0000u);
      float r2 = r1 - md;                     // exact (<=8 sig bits)
      unsigned int u3 = __float_as_uint(r2);
      ah[j] = (short)(u >> 16);
      am_[j] = (short)(u2 >> 16);
      al[j] = (short)(u3 >> 16);
    }
    // B frag: k = s*32 + quad*8 + j -> dwords (s*8 + quad*2) + {0,1}
    const int dw = s * 8 + quad * 2;
    unsigned int d0 = idx32[dw], d1 = idx32[dw + 1];
    short8 b0, b1;
#pragma unroll
    for (int j = 0; j < 8; ++j) {
      unsigned int byte = ((j < 4 ? d0 : d1) >> ((j & 3) * 8)) & 0xFFu;
      b0[j] = (byte == (unsigned int)n16) ? (short)0x3F80 : (short)0;
      b1[j] = (byte == (unsigned int)(n16 + 16)) ? (short)0x3F80 : (short)0;
    }
    acc0 = __builtin_amdgcn_mfma_f32_16x16x32_bf16(ah, b0, acc0, 0, 0, 0);
    acc0 = __builtin_amdgcn_mfma_f32_16x16x32_bf16(am_, b0, acc0, 0, 0, 0);
    acc0 = __builtin_amdgcn_mfma_f32_16x16x32_bf16(al, b0, acc0, 0, 0, 0);
    acc1 = __builtin_amdgcn_mfma_f32_16x16x32_bf16(ah, b1, acc1, 0, 0, 0);
    acc1 = __builtin_amdgcn_mfma_f32_16x16x32_bf16(am_, b1, acc1, 0, 0, 0);
    acc1 = __builtin_amdgcn_mfma_f32_16x16x32_bf16(al, b1, acc1, 0, 0, 0);
  }
  // ---- write C rows 0..10 to LDS (row = quad*4 + reg, col = n16) ----
#pragma unroll
  for (int r = 0; r < 4; ++r) {
    int row = quad * 4 + r;
    if (row < 11) {
      Cs[row][n16] = acc0[r];
      if (n16 < 2) Cs[row][16 + n16] = acc1[r];
    }
  }
  __syncthreads();
  // ---- MI ----
  if (lane < 10) {
    float tot = 0.f, mb_[18];
#pragma unroll
    for (int b = 0; b < 18; ++b) {
      float mb = Cs[lane][b] / fmaxf(Cs[10][b], 1.0f);
      mb_[b] = mb; tot += mb;
    }
    tot = fmaxf(tot, 1e-12f);
    float s = 0.f;
#pragma unroll
    for (int b = 0; b < 18; ++b) {
      float pb = mb_[b] / tot;
      s += pb * logf(fmaxf(pb, 1e-12f));
    }
    const float LOGN = 2.8903717578961645f; // log(18)
    mi[(size_t)blk * 10 + lane] = (LOGN + s) / LOGN;
  }
}

// ---------------------------------------------------------------------------
// Kernel D: mean over the scrambled s' axis -> out (4,8,10,10)
// ---------------------------------------------------------------------------
__global__ void out_kernel(const float* __restrict__ mi, float* __restrict__ out) {
  int i = blockIdx.x * 256 + threadIdx.x;
  if (i < 3200) {
    int a = i % 10, p = (i / 10) % 10, bc = i / 100;
    float s = 0.f;
    for (int sp = 0; sp < 4; ++sp)
      s += mi[((size_t)(bc * 40 + p * 4 + sp)) * 10 + a];
    out[i] = 0.25f * s;
  }
}

extern "C" void kernel_launch(void* const* d_in, const int* in_sizes, int n_in,
                              void* d_out, int out_size, void* d_ws, size_t ws_size,
                              hipStream_t stream) {
  (void)in_sizes; (void)n_in; (void)out_size; (void)ws_size;
  const float* x = (const float*)d_in[0];     // (4,8,4,2048) fp32
  const float* ker = (const float*)d_in[1];   // (20,769) fp32
  float* out = (float*)d_out;                 // 3200 fp32
  float* filt = (float*)d_ws;                 // 128*20*2048 fp32 (~21 MB)
  float* mi = filt + (size_t)NS * NF * TT;    // 12800 fp32

  conv_kernel<<<NS * 10, 256, 0, stream>>>(x, ker, filt);
  hilbert_kernel<<<NS * NF / 2, 256, 0, stream>>>(filt);
  mi_kernel<<<32 * 40, 64, 0, stream>>>(filt, mi);
  out_kernel<<<(3200 + 255) / 256, 256, 0, stream>>>(mi, out);
}

// Round 13
// 163.226 us; speedup vs baseline: 1.2404x; 1.0417x over previous
//
#include <hip/hip_runtime.h>
#include <math.h>

#define TT 2048
#define LK 769
#define NF 20
#define NS 128
#define NB 18

typedef __attribute__((ext_vector_type(8))) short short8;
typedef __attribute__((ext_vector_type(4))) float f32x4;

// ---------------------------------------------------------------------------
// Kernel A: symmetric FIR conv (unchanged from R10).
// ---------------------------------------------------------------------------
__global__ __launch_bounds__(256) void conv_kernel(const float* __restrict__ x,
                                                   const float* __restrict__ ker,
                                                   float* __restrict__ filt) {
  __shared__ __align__(16) float w[2832];   // spad[384..3200) + zero tail
  __shared__ __align__(16) float hs1[784];  // symmetrized pha filter
  __shared__ __align__(16) float hs2[784];  // symmetrized amp filter
  __shared__ int red[4][4];
  const int tid = threadIdx.x;
  const int ord = blockIdx.x;
  const int p = ord / NS;                   // 0..9, longest pair first
  const int n = ord % NS;
  const int o1 = p;                          // pha band
  const int o2 = 10 + (9 - p);               // amp band (short with long)
  const float* xr = x + n * TT;
  for (int j = tid; j < 2832; j += 256) {
    float v = 0.f;
    if (j < 2816) {
      int m = j - 384;              // spad[j+384] -> original index (j+384)-768
      if (m < 0) m = -m;            // reflect (edge excluded)
      if (m > 2047) m = 4094 - m;
      v = xr[m];
    }
    w[j] = v;
  }
  const float* kr1 = ker + o1 * LK;
  const float* kr2 = ker + o2 * LK;
  int k0 = 784, k1 = 0, m0 = 784, m1 = 0;
  for (int k = tid; k < 784; k += 256) {
    float v1 = 0.f, v2 = 0.f;
    if (k < LK) {
      v1 = 0.5f * (kr1[k] + kr1[LK - 1 - k]);
      v2 = 0.5f * (kr2[k] + kr2[LK - 1 - k]);
    }
    hs1[k] = v1;
    hs2[k] = v2;
    if (v1 != 0.f) { k0 = min(k0, k); k1 = max(k1, k + 1); }
    if (v2 != 0.f) { m0 = min(m0, k); m1 = max(m1, k + 1); }
  }
#pragma unroll
  for (int off = 32; off > 0; off >>= 1) {
    k0 = min(k0, __shfl_down(k0, off));
    k1 = max(k1, __shfl_down(k1, off));
    m0 = min(m0, __shfl_down(m0, off));
    m1 = max(m1, __shfl_down(m1, off));
  }
  const int wid = tid >> 6;
  if ((tid & 63) == 0) { red[wid][0] = k0; red[wid][1] = k1; red[wid][2] = m0; red[wid][3] = m1; }
  __syncthreads();
  k0 = min(min(red[0][0], red[1][0]), min(red[2][0], red[3][0]));
  k1 = max(max(red[0][1], red[1][1]), max(red[2][1], red[3][1]));
  m0 = min(min(red[0][2], red[1][2]), min(red[2][2], red[3][2]));
  m1 = max(max(red[0][3], red[1][3]), max(red[2][3], red[3][3]));
  // 8-aligned ranges (extra taps are exact zeros -> bit-exact)
  const int A0 = __builtin_amdgcn_readfirstlane(k0 & ~7);
  const int A1 = __builtin_amdgcn_readfirstlane((k1 + 7) & ~7);
  const int B0 = __builtin_amdgcn_readfirstlane(m0 & ~7);
  const int B1 = __builtin_amdgcn_readfirstlane((m1 + 7) & ~7);
  const int U0 = min(A0, B0);
  const int U1 = max(A1, B1);

  const int bA = 4 * tid;           // group A outputs [bA, bA+4)
  const int bB = 1024 + 4 * tid;    // group B outputs [bB, bB+4)
  float acc1A[4], acc1B[4], acc2A[4], acc2B[4];
#pragma unroll
  for (int r = 0; r < 4; ++r) { acc1A[r] = 0.f; acc1B[r] = 0.f; acc2A[r] = 0.f; acc2B[r] = 0.f; }
  if (U0 < U1) {
    // rolling window: a0..a2 cover w[bA+k .. bA+k+12)
    float4 a0 = *(const float4*)&w[bA + U0];
    float4 a1 = *(const float4*)&w[bA + U0 + 4];
    float4 a2 = *(const float4*)&w[bA + U0 + 8];
    float4 b0 = *(const float4*)&w[bB + U0];
    float4 b1 = *(const float4*)&w[bB + U0 + 4];
    float4 b2 = *(const float4*)&w[bB + U0 + 8];
    float4 h1a = *(const float4*)&hs1[U0];
    float4 h1b = *(const float4*)&hs1[U0 + 4];
    float4 h2a = *(const float4*)&hs2[U0];
    float4 h2b = *(const float4*)&hs2[U0 + 4];
    for (int k = U0; k < U1; k += 8) {
      float4 a3 = *(const float4*)&w[bA + k + 12];
      float4 a4 = *(const float4*)&w[bA + k + 16];
      float4 b3 = *(const float4*)&w[bB + k + 12];
      float4 b4 = *(const float4*)&w[bB + k + 16];
      float4 h1an = *(const float4*)&hs1[k + 8];
      float4 h1bn = *(const float4*)&hs1[k + 12];
      float4 h2an = *(const float4*)&hs2[k + 8];
      float4 h2bn = *(const float4*)&hs2[k + 12];
      float wa[11] = {a0.x, a0.y, a0.z, a0.w, a1.x, a1.y, a1.z, a1.w,
                      a2.x, a2.y, a2.z};
      float wb[11] = {b0.x, b0.y, b0.z, b0.w, b1.x, b1.y, b1.z, b1.w,
                      b2.x, b2.y, b2.z};
      float h1[8] = {h1a.x, h1a.y, h1a.z, h1a.w, h1b.x, h1b.y, h1b.z, h1b.w};
      float h2[8] = {h2a.x, h2a.y, h2a.z, h2a.w, h2b.x, h2b.y, h2b.z, h2b.w};
      if (k >= A0 && k < A1) {
#pragma unroll
        for (int r = 0; r < 4; ++r) {
#pragma unroll
          for (int j = 0; j < 8; ++j) {
            acc1A[r] = fmaf(h1[j], wa[r + j], acc1A[r]);
            acc1B[r] = fmaf(h1[j], wb[r + j], acc1B[r]);
          }
        }
      }
      if (k >= B0 && k < B1) {
#pragma unroll
        for (int r = 0; r < 4; ++r) {
#pragma unroll
          for (int j = 0; j < 8; ++j) {
            acc2A[r] = fmaf(h2[j], wa[r + j], acc2A[r]);
            acc2B[r] = fmaf(h2[j], wb[r + j], acc2B[r]);
          }
        }
      }
      a0 = a2; a1 = a3; a2 = a4;
      b0 = b2; b1 = b3; b2 = b4;
      h1a = h1an; h1b = h1bn;
      h2a = h2an; h2b = h2bn;
    }
  }
  float* out1 = filt + ((size_t)n * NF + o1) * TT;
  float* out2 = filt + ((size_t)n * NF + o2) * TT;
  *(float4*)&out1[bA] = make_float4(acc1A[0], acc1A[1], acc1A[2], acc1A[3]);
  *(float4*)&out1[bB] = make_float4(acc1B[0], acc1B[1], acc1B[2], acc1B[3]);
  *(float4*)&out2[bA] = make_float4(acc2A[0], acc2A[1], acc2A[2], acc2A[3]);
  *(float4*)&out2[bB] = make_float4(acc2B[0], acc2B[1], acc2B[2], acc2B[3]);
}

// ---------------------------------------------------------------------------
// Kernel B: Hilbert via mixed-radix FFT, R13: radix-2 (half=1024) + 5x
// radix-4 DIF forward; 5x radix-4 DIT + radix-2 inverse. Halves DS ops and
// barriers vs all-radix-2 (22 stages -> 12). Output order of fwd:
// p = (bit0 of k)<<10 | digitrev4(k>>1); bit10 of k == bit1 of p, so the
// Hilbert mask in this space is: p==0 (k=0), p==2 (k=1024) -> x1;
// (p&2)==0 -> x2; else 0.  Twiddles: W_{4Q}^j = tw[2Q+j], W^{2j} = tw[Q+j],
// W^{3j} = W^j*W^{2j}.  Two rows per block via z = x1 + i*x2 as before.
// ---------------------------------------------------------------------------
__global__ __launch_bounds__(256) void hilbert_kernel(float* __restrict__ filt) {
  __shared__ __align__(16) float2 z[TT];
  __shared__ __align__(16) float2 tw[TT];  // tw[half+j] = exp(-i*pi*j/half)
  const int tid = threadIdx.x;
  const int blk = blockIdx.x;          // rows 2*blk, 2*blk+1
  float* row1 = filt + (size_t)(2 * blk) * TT;
  float* row2 = row1 + TT;
  for (int i = tid; i < TT; i += 256) {
    if (i == 0) { tw[0] = make_float2(1.f, 0.f); }
    else {
      int half = 1 << (31 - __clz(i));
      int j = i - half;
      float ang = -3.14159265358979323846f * (float)j / (float)half;
      float s, c;
      sincosf(ang, &s, &c);
      tw[i] = make_float2(c, s);
    }
    z[i] = make_float2(row1[i], row2[i]);
  }
  __syncthreads();
  // ---- forward radix-2 DIF stage (half=1024) ----
  for (int bf = tid; bf < 1024; bf += 256) {
    const float2 t = tw[1024 + bf];
    const float2 u = z[bf];
    const float2 v = z[bf + 1024];
    z[bf] = make_float2(u.x + v.x, u.y + v.y);
    const float dr = u.x - v.x, di = u.y - v.y;
    z[bf + 1024] = make_float2(fmaf(t.x, dr, -(t.y * di)),
                               fmaf(t.x, di, t.y * dr));
  }
  __syncthreads();
  // ---- forward radix-4 DIF stages: Q = 256,64,16,4,1 ----
  for (int Q = 256; Q >= 1; Q >>= 2) {
    for (int bf = tid; bf < 512; bf += 256) {
      const int j = bf & (Q - 1);
      const int base = ((bf & ~(Q - 1)) << 2) + j;
      const float2 x0 = z[base], x1 = z[base + Q];
      const float2 x2 = z[base + 2 * Q], x3 = z[base + 3 * Q];
      const float2 w1 = tw[2 * Q + j];
      const float2 w2 = tw[Q + j];
      const float w3r = w1.x * w2.x - w1.y * w2.y;
      const float w3i = w1.x * w2.y + w1.y * w2.x;
      const float t0r = x0.x + x2.x, t0i = x0.y + x2.y;
      const float t1r = x0.x - x2.x, t1i = x0.y - x2.y;
      const float t2r = x1.x + x3.x, t2i = x1.y + x3.y;
      const float t3r = x1.x - x3.x, t3i = x1.y - x3.y;
      z[base] = make_float2(t0r + t2r, t0i + t2i);
      const float a1r = t1r + t3i, a1i = t1i - t3r;     // (t1 - i t3)
      z[base + Q] = make_float2(a1r * w1.x - a1i * w1.y,
                                a1r * w1.y + a1i * w1.x);
      const float a2r = t0r - t2r, a2i = t0i - t2i;
      z[base + 2 * Q] = make_float2(a2r * w2.x - a2i * w2.y,
                                    a2r * w2.y + a2i * w2.x);
      const float a3r = t1r - t3i, a3i = t1i + t3r;     // (t1 + i t3)
      z[base + 3 * Q] = make_float2(a3r * w3r - a3i * w3i,
                                    a3r * w3i + a3i * w3r);
    }
    __syncthreads();
  }
  // ---- Hilbert mask in mixed-digit-reversed space ----
  for (int pp = tid; pp < TT; pp += 256) {
    if (pp != 0 && pp != 2) {
      if (pp & 2) { z[pp] = make_float2(0.f, 0.f); }
      else        { float2 v = z[pp]; z[pp] = make_float2(2.f * v.x, 2.f * v.y); }
    }
  }
  __syncthreads();
  // ---- inverse radix-4 DIT stages: Q = 1,4,16,64,256 (conj twiddles) ----
  for (int Q = 1; Q <= 256; Q <<= 2) {
    for (int bf = tid; bf < 512; bf += 256) {
      const int j = bf & (Q - 1);
      const int base = ((bf & ~(Q - 1)) << 2) + j;
      const float2 y0 = z[base], y1 = z[base + Q];
      const float2 y2 = z[base + 2 * Q], y3 = z[base + 3 * Q];
      const float2 w1 = tw[2 * Q + j];
      const float2 w2 = tw[Q + j];
      const float w3r = w1.x * w2.x - w1.y * w2.y;
      const float w3i = w1.x * w2.y + w1.y * w2.x;
      // u_m = y_m * conj(w_m)
      const float u1r = y1.x * w1.x + y1.y * w1.y;
      const float u1i = y1.y * w1.x - y1.x * w1.y;
      const float u2r = y2.x * w2.x + y2.y * w2.y;
      const float u2i = y2.y * w2.x - y2.x * w2.y;
      const float u3r = y3.x * w3r + y3.y * w3i;
      const float u3i = y3.y * w3r - y3.x * w3i;
      const float t0r = y0.x + u2r, t0i = y0.y + u2i;
      const float t1r = y0.x - u2r, t1i = y0.y - u2i;
      const float t2r = u1r + u3r, t2i = u1i + u3i;
      const float t3r = u1r - u3r, t3i = u1i - u3i;
      z[base]         = make_float2(t0r + t2r, t0i + t2i);
      z[base + Q]     = make_float2(t1r - t3i, t1i + t3r);  // t1 + i t3
      z[base + 2 * Q] = make_float2(t0r - t2r, t0i - t2i);
      z[base + 3 * Q] = make_float2(t1r + t3i, t1i - t3r);  // t1 - i t3
    }
    __syncthreads();
  }
  // ---- inverse radix-2 DIT stage (half=1024, conj twiddle) ----
  for (int bf = tid; bf < 1024; bf += 256) {
    const float2 t = tw[1024 + bf];
    const float2 u = z[bf];
    const float2 v = z[bf + 1024];
    const float vr = v.x * t.x + v.y * t.y;
    const float vi = v.y * t.x - v.x * t.y;
    z[bf] = make_float2(u.x + vr, u.y + vi);
    z[bf + 1024] = make_float2(u.x - vr, u.y - vi);
  }
  __syncthreads();
  // ---- recover h1,h2; write phase/amp ----
  const int o1 = (2 * blk) % NF;       // even -> pair never crosses pha/amp
  const bool p1 = o1 < 10, p2 = (o1 + 1) < 10;
  const float invN = 1.0f / 2048.0f;
  for (int t = tid; t < TT; t += 256) {
    float x1 = row1[t], x2 = row2[t];
    float2 wv = z[t];
    float wr = wv.x * invN, wi = wv.y * invN;
    float h1 = wi - x2;
    float h2 = x1 - wr;
    row1[t] = p1 ? atan2f(h1, x1) : sqrtf(fmaf(x1, x1, h1 * h1));
    row2[t] = p2 ? atan2f(h2, x2) : sqrtf(fmaf(x2, x2, h2 * h2));
  }
}

// ---------------------------------------------------------------------------
// Kernel C: binned MI via MFMA (unchanged from R12 — verified 16x16x32
// layouts, 3-way exact bf16 split, counts via ones-row).
// ---------------------------------------------------------------------------
__global__ __launch_bounds__(64) void mi_kernel(const float* __restrict__ filt,
                                                float* __restrict__ mi) {
  __shared__ __align__(16) unsigned int idx32[512];  // 4 bins/dword
  __shared__ float Cs[12][19];
  const int lane = threadIdx.x;
  const int blk = blockIdx.x;           // bc*40 + jp
  const int bc = blk / 40, jp = blk % 40;
  const float* ph = filt + ((size_t)(bc * 4 + jp / 10) * NF + (jp % 10)) * TT;
  for (int g = lane; g < 512; g += 64) {
    float4 v = *(const float4*)&ph[4 * g];
    float vv[4] = {v.x, v.y, v.z, v.w};
    unsigned int packed = 0;
#pragma unroll
    for (int j = 0; j < 4; ++j) {
      int b = (int)floorf((vv[j] + 3.14159274f) / 6.2831855f * 18.0f);
      b = b < 0 ? 0 : (b > 17 ? 17 : b);
      packed |= ((unsigned int)b) << (8 * j);
    }
    idx32[g] = packed;
  }
  __syncthreads();
  const int n16 = lane & 15;    // A row m / B col n / C col
  const int quad = lane >> 4;   // k-quad (0..3)
  const int aband = n16 < 10 ? n16 : 9;
  const int ja = (jp & 3) + 4 * aband;   // scrambled amp row, same s'
  const float* aptr = filt + ((size_t)(bc * 4 + ja / 10) * NF + 10 + (ja % 10)) * TT
                      + quad * 8;
  const bool isAmp = (n16 < 10);
  const bool isOne = (n16 == 10);
  f32x4 acc0 = {0.f, 0.f, 0.f, 0.f};     // bins 0..15
  f32x4 acc1 = {0.f, 0.f, 0.f, 0.f};     // bins 16..17 (cols 16+n16)
  float4 p0 = *(const float4*)(aptr);
  float4 p1 = *(const float4*)(aptr + 4);
  for (int s = 0; s < 64; ++s) {
    float4 c0 = p0, c1 = p1;
    if (s < 63) {
      p0 = *(const float4*)(aptr + (s + 1) * 32);
      p1 = *(const float4*)(aptr + (s + 1) * 32 + 4);
    }
    float a[8] = {c0.x, c0.y, c0.z, c0.w, c1.x, c1.y, c1.z, c1.w};
    short8 ah, am_, al;
#pragma unroll
    for (int j = 0; j < 8; ++j) {
      float v = isAmp ? a[j] : (isOne ? 1.0f : 0.0f);
      unsigned int u = __float_as_uint(v);
      float h = __uint_as_float(u & 0xFFFF0000u);
      float r1 = v - h;                       // exact (<=16 sig bits)
      unsigned int u2 = __float_as_uint(r1);
      float md = __uint_as_float(u2 & 0xFFFF0000u);
      float r2 = r1 - md;                     // exact (<=8 sig bits)
      unsigned int u3 = __float_as_uint(r2);
      ah[j] = (short)(u >> 16);
      am_[j] = (short)(u2 >> 16);
      al[j] = (short)(u3 >> 16);
    }
    const int dw = s * 8 + quad * 2;
    unsigned int d0 = idx32[dw], d1 = idx32[dw + 1];
    short8 b0, b1;
#pragma unroll
    for (int j = 0; j < 8; ++j) {
      unsigned int byte = ((j < 4 ? d0 : d1) >> ((j & 3) * 8)) & 0xFFu;
      b0[j] = (byte == (unsigned int)n16) ? (short)0x3F80 : (short)0;
      b1[j] = (byte == (unsigned int)(n16 + 16)) ? (short)0x3F80 : (short)0;
    }
    acc0 = __builtin_amdgcn_mfma_f32_16x16x32_bf16(ah, b0, acc0, 0, 0, 0);
    acc0 = __builtin_amdgcn_mfma_f32_16x16x32_bf16(am_, b0, acc0, 0, 0, 0);
    acc0 = __builtin_amdgcn_mfma_f32_16x16x32_bf16(al, b0, acc0, 0, 0, 0);
    acc1 = __builtin_amdgcn_mfma_f32_16x16x32_bf16(ah, b1, acc1, 0, 0, 0);
    acc1 = __builtin_amdgcn_mfma_f32_16x16x32_bf16(am_, b1, acc1, 0, 0, 0);
    acc1 = __builtin_amdgcn_mfma_f32_16x16x32_bf16(al, b1, acc1, 0, 0, 0);
  }
#pragma unroll
  for (int r = 0; r < 4; ++r) {
    int row = quad * 4 + r;
    if (row < 11) {
      Cs[row][n16] = acc0[r];
      if (n16 < 2) Cs[row][16 + n16] = acc1[r];
    }
  }
  __syncthreads();
  if (lane < 10) {
    float tot = 0.f, mb_[18];
#pragma unroll
    for (int b = 0; b < 18; ++b) {
      float mb = Cs[lane][b] / fmaxf(Cs[10][b], 1.0f);
      mb_[b] = mb; tot += mb;
    }
    tot = fmaxf(tot, 1e-12f);
    float s = 0.f;
#pragma unroll
    for (int b = 0; b < 18; ++b) {
      float pb = mb_[b] / tot;
      s += pb * logf(fmaxf(pb, 1e-12f));
    }
    const float LOGN = 2.8903717578961645f; // log(18)
    mi[(size_t)blk * 10 + lane] = (LOGN + s) / LOGN;
  }
}

// ---------------------------------------------------------------------------
// Kernel D: mean over the scrambled s' axis -> out (4,8,10,10)
// ---------------------------------------------------------------------------
__global__ void out_kernel(const float* __restrict__ mi, float* __restrict__ out) {
  int i = blockIdx.x * 256 + threadIdx.x;
  if (i < 3200) {
    int a = i % 10, p = (i / 10) % 10, bc = i / 100;
    float s = 0.f;
    for (int sp = 0; sp < 4; ++sp)
      s += mi[((size_t)(bc * 40 + p * 4 + sp)) * 10 + a];
    out[i] = 0.25f * s;
  }
}

extern "C" void kernel_launch(void* const* d_in, const int* in_sizes, int n_in,
                              void* d_out, int out_size, void* d_ws, size_t ws_size,
                              hipStream_t stream) {
  (void)in_sizes; (void)n_in; (void)out_size; (void)ws_size;
  const float* x = (const float*)d_in[0];     // (4,8,4,2048) fp32
  const float* ker = (const float*)d_in[1];   // (20,769) fp32
  float* out = (float*)d_out;                 // 3200 fp32
  float* filt = (float*)d_ws;                 // 128*20*2048 fp32 (~21 MB)
  float* mi = filt + (size_t)NS * NF * TT;    // 12800 fp32

  conv_kernel<<<NS * 10, 256, 0, stream>>>(x, ker, filt);
  hilbert_kernel<<<NS * NF / 2, 256, 0, stream>>>(filt);
  mi_kernel<<<32 * 40, 64, 0, stream>>>(filt, mi);
  out_kernel<<<(3200 + 255) / 256, 256, 0, stream>>>(mi, out);
}

// Round 14
// 151.562 us; speedup vs baseline: 1.3359x; 1.0770x over previous
//
#include <hip/hip_runtime.h>
#include <math.h>

#define TT 2048
#define LK 769
#define NF 20
#define NS 128
#define NB 18

typedef __attribute__((ext_vector_type(8))) short short8;
typedef __attribute__((ext_vector_type(4))) float f32x4;

// ---------------------------------------------------------------------------
// Kernel A: FUSED conv + Hilbert. One wg per (signal, filter-PAIR)
// (o1 = pha band p, o2 = amp band 9-p). Conv part identical to R10-R13
// (symmetrized taps, 8-tap rolling-window iters, bit-exact). Conv outputs
// stay in registers; z = out1 + i*out2 goes into LDS (overlaying the dead
// conv window/taps region), then the R13 mixed-radix FFT Hilbert runs
// in-place, and the epilogue computes phase (o1) / amp (o2) using x1,x2
// still in registers (thread owns t in {4*tid..+3, 1024+4*tid..+3} for both
// conv outputs and FFT epilogue). Saves the 21MB filt write + 42MB re-read
// and one dispatch vs the split version.
// ---------------------------------------------------------------------------
__global__ __launch_bounds__(256) void convhil_kernel(const float* __restrict__ x,
                                                      const float* __restrict__ ker,
                                                      float* __restrict__ filt) {
  __shared__ __align__(16) float smem[4400];   // w[2832]+hs1[784]+hs2[784]; z overlays
  __shared__ int red[4][4];
  __shared__ __align__(16) float2 tw[TT];      // tw[half+j] = exp(-i*pi*j/half)
  float* w   = smem;
  float* hs1 = smem + 2832;
  float* hs2 = smem + 3616;
  float2* z  = (float2*)smem;                  // 2048 float2 = 4096 floats < 4400
  const int tid = threadIdx.x;
  const int ord = blockIdx.x;
  const int p = ord / NS;                   // 0..9, longest pair first
  const int n = ord % NS;
  const int o1 = p;                          // pha band
  const int o2 = 10 + (9 - p);               // amp band (short with long)
  const float* xr = x + n * TT;
  for (int j = tid; j < 2832; j += 256) {
    float v = 0.f;
    if (j < 2816) {
      int m = j - 384;              // spad[j+384] -> original index (j+384)-768
      if (m < 0) m = -m;            // reflect (edge excluded)
      if (m > 2047) m = 4094 - m;
      v = xr[m];
    }
    w[j] = v;
  }
  // twiddle table (separate LDS region, live for the whole kernel)
  for (int i = tid; i < TT; i += 256) {
    if (i == 0) { tw[0] = make_float2(1.f, 0.f); }
    else {
      int half = 1 << (31 - __clz(i));
      int j = i - half;
      float ang = -3.14159265358979323846f * (float)j / (float)half;
      float s, c;
      sincosf(ang, &s, &c);
      tw[i] = make_float2(c, s);
    }
  }
  const float* kr1 = ker + o1 * LK;
  const float* kr2 = ker + o2 * LK;
  int k0 = 784, k1 = 0, m0 = 784, m1 = 0;
  for (int k = tid; k < 784; k += 256) {
    float v1 = 0.f, v2 = 0.f;
    if (k < LK) {
      v1 = 0.5f * (kr1[k] + kr1[LK - 1 - k]);
      v2 = 0.5f * (kr2[k] + kr2[LK - 1 - k]);
    }
    hs1[k] = v1;
    hs2[k] = v2;
    if (v1 != 0.f) { k0 = min(k0, k); k1 = max(k1, k + 1); }
    if (v2 != 0.f) { m0 = min(m0, k); m1 = max(m1, k + 1); }
  }
#pragma unroll
  for (int off = 32; off > 0; off >>= 1) {
    k0 = min(k0, __shfl_down(k0, off));
    k1 = max(k1, __shfl_down(k1, off));
    m0 = min(m0, __shfl_down(m0, off));
    m1 = max(m1, __shfl_down(m1, off));
  }
  const int wid = tid >> 6;
  if ((tid & 63) == 0) { red[wid][0] = k0; red[wid][1] = k1; red[wid][2] = m0; red[wid][3] = m1; }
  __syncthreads();
  k0 = min(min(red[0][0], red[1][0]), min(red[2][0], red[3][0]));
  k1 = max(max(red[0][1], red[1][1]), max(red[2][1], red[3][1]));
  m0 = min(min(red[0][2], red[1][2]), min(red[2][2], red[3][2]));
  m1 = max(max(red[0][3], red[1][3]), max(red[2][3], red[3][3]));
  // 8-aligned ranges (extra taps are exact zeros -> bit-exact)
  const int A0 = __builtin_amdgcn_readfirstlane(k0 & ~7);
  const int A1 = __builtin_amdgcn_readfirstlane((k1 + 7) & ~7);
  const int B0 = __builtin_amdgcn_readfirstlane(m0 & ~7);
  const int B1 = __builtin_amdgcn_readfirstlane((m1 + 7) & ~7);
  const int U0 = min(A0, B0);
  const int U1 = max(A1, B1);

  const int bA = 4 * tid;           // group A outputs [bA, bA+4)
  const int bB = 1024 + 4 * tid;    // group B outputs [bB, bB+4)
  float acc1A[4], acc1B[4], acc2A[4], acc2B[4];
#pragma unroll
  for (int r = 0; r < 4; ++r) { acc1A[r] = 0.f; acc1B[r] = 0.f; acc2A[r] = 0.f; acc2B[r] = 0.f; }
  if (U0 < U1) {
    // rolling window: a0..a2 cover w[bA+k .. bA+k+12)
    float4 a0 = *(const float4*)&w[bA + U0];
    float4 a1 = *(const float4*)&w[bA + U0 + 4];
    float4 a2 = *(const float4*)&w[bA + U0 + 8];
    float4 b0 = *(const float4*)&w[bB + U0];
    float4 b1 = *(const float4*)&w[bB + U0 + 4];
    float4 b2 = *(const float4*)&w[bB + U0 + 8];
    float4 h1a = *(const float4*)&hs1[U0];
    float4 h1b = *(const float4*)&hs1[U0 + 4];
    float4 h2a = *(const float4*)&hs2[U0];
    float4 h2b = *(const float4*)&hs2[U0 + 4];
    for (int k = U0; k < U1; k += 8) {
      float4 a3 = *(const float4*)&w[bA + k + 12];
      float4 a4 = *(const float4*)&w[bA + k + 16];
      float4 b3 = *(const float4*)&w[bB + k + 12];
      float4 b4 = *(const float4*)&w[bB + k + 16];
      float4 h1an = *(const float4*)&hs1[k + 8];
      float4 h1bn = *(const float4*)&hs1[k + 12];
      float4 h2an = *(const float4*)&hs2[k + 8];
      float4 h2bn = *(const float4*)&hs2[k + 12];
      float wa[11] = {a0.x, a0.y, a0.z, a0.w, a1.x, a1.y, a1.z, a1.w,
                      a2.x, a2.y, a2.z};
      float wb[11] = {b0.x, b0.y, b0.z, b0.w, b1.x, b1.y, b1.z, b1.w,
                      b2.x, b2.y, b2.z};
      float h1[8] = {h1a.x, h1a.y, h1a.z, h1a.w, h1b.x, h1b.y, h1b.z, h1b.w};
      float h2[8] = {h2a.x, h2a.y, h2a.z, h2a.w, h2b.x, h2b.y, h2b.z, h2b.w};
      if (k >= A0 && k < A1) {
#pragma unroll
        for (int r = 0; r < 4; ++r) {
#pragma unroll
          for (int j = 0; j < 8; ++j) {
            acc1A[r] = fmaf(h1[j], wa[r + j], acc1A[r]);
            acc1B[r] = fmaf(h1[j], wb[r + j], acc1B[r]);
          }
        }
      }
      if (k >= B0 && k < B1) {
#pragma unroll
        for (int r = 0; r < 4; ++r) {
#pragma unroll
          for (int j = 0; j < 8; ++j) {
            acc2A[r] = fmaf(h2[j], wa[r + j], acc2A[r]);
            acc2B[r] = fmaf(h2[j], wb[r + j], acc2B[r]);
          }
        }
      }
      a0 = a2; a1 = a3; a2 = a4;
      b0 = b2; b1 = b3; b2 = b4;
      h1a = h1an; h1b = h1bn;
      h2a = h2an; h2b = h2bn;
    }
  }
  // ---- hand off to FFT: z = out1 + i*out2 (overlays dead w/hs region) ----
  __syncthreads();                    // everyone done reading w/hs
#pragma unroll
  for (int r = 0; r < 4; ++r) {
    z[bA + r] = make_float2(acc1A[r], acc2A[r]);
    z[bB + r] = make_float2(acc1B[r], acc2B[r]);
  }
  __syncthreads();
  // ---- forward radix-2 DIF stage (half=1024) ----
  for (int bf = tid; bf < 1024; bf += 256) {
    const float2 t = tw[1024 + bf];
    const float2 u = z[bf];
    const float2 v = z[bf + 1024];
    z[bf] = make_float2(u.x + v.x, u.y + v.y);
    const float dr = u.x - v.x, di = u.y - v.y;
    z[bf + 1024] = make_float2(fmaf(t.x, dr, -(t.y * di)),
                               fmaf(t.x, di, t.y * dr));
  }
  __syncthreads();
  // ---- forward radix-4 DIF stages: Q = 256,64,16,4,1 ----
  for (int Q = 256; Q >= 1; Q >>= 2) {
    for (int bf = tid; bf < 512; bf += 256) {
      const int j = bf & (Q - 1);
      const int base = ((bf & ~(Q - 1)) << 2) + j;
      const float2 x0 = z[base], x1 = z[base + Q];
      const float2 x2 = z[base + 2 * Q], x3 = z[base + 3 * Q];
      const float2 w1 = tw[2 * Q + j];
      const float2 w2 = tw[Q + j];
      const float w3r = w1.x * w2.x - w1.y * w2.y;
      const float w3i = w1.x * w2.y + w1.y * w2.x;
      const float t0r = x0.x + x2.x, t0i = x0.y + x2.y;
      const float t1r = x0.x - x2.x, t1i = x0.y - x2.y;
      const float t2r = x1.x + x3.x, t2i = x1.y + x3.y;
      const float t3r = x1.x - x3.x, t3i = x1.y - x3.y;
      z[base] = make_float2(t0r + t2r, t0i + t2i);
      const float a1r = t1r + t3i, a1i = t1i - t3r;     // (t1 - i t3)
      z[base + Q] = make_float2(a1r * w1.x - a1i * w1.y,
                                a1r * w1.y + a1i * w1.x);
      const float a2r = t0r - t2r, a2i = t0i - t2i;
      z[base + 2 * Q] = make_float2(a2r * w2.x - a2i * w2.y,
                                    a2r * w2.y + a2i * w2.x);
      const float a3r = t1r - t3i, a3i = t1i + t3r;     // (t1 + i t3)
      z[base + 3 * Q] = make_float2(a3r * w3r - a3i * w3i,
                                    a3r * w3i + a3i * w3r);
    }
    __syncthreads();
  }
  // ---- Hilbert mask in mixed-digit-reversed space ----
  for (int pp = tid; pp < TT; pp += 256) {
    if (pp != 0 && pp != 2) {
      if (pp & 2) { z[pp] = make_float2(0.f, 0.f); }
      else        { float2 v = z[pp]; z[pp] = make_float2(2.f * v.x, 2.f * v.y); }
    }
  }
  __syncthreads();
  // ---- inverse radix-4 DIT stages: Q = 1,4,16,64,256 (conj twiddles) ----
  for (int Q = 1; Q <= 256; Q <<= 2) {
    for (int bf = tid; bf < 512; bf += 256) {
      const int j = bf & (Q - 1);
      const int base = ((bf & ~(Q - 1)) << 2) + j;
      const float2 y0 = z[base], y1 = z[base + Q];
      const float2 y2 = z[base + 2 * Q], y3 = z[base + 3 * Q];
      const float2 w1 = tw[2 * Q + j];
      const float2 w2 = tw[Q + j];
      const float w3r = w1.x * w2.x - w1.y * w2.y;
      const float w3i = w1.x * w2.y + w1.y * w2.x;
      // u_m = y_m * conj(w_m)
      const float u1r = y1.x * w1.x + y1.y * w1.y;
      const float u1i = y1.y * w1.x - y1.x * w1.y;
      const float u2r = y2.x * w2.x + y2.y * w2.y;
      const float u2i = y2.y * w2.x - y2.x * w2.y;
      const float u3r = y3.x * w3r + y3.y * w3i;
      const float u3i = y3.y * w3r - y3.x * w3i;
      const float t0r = y0.x + u2r, t0i = y0.y + u2i;
      const float t1r = y0.x - u2r, t1i = y0.y - u2i;
      const float t2r = u1r + u3r, t2i = u1i + u3i;
      const float t3r = u1r - u3r, t3i = u1i - u3i;
      z[base]         = make_float2(t0r + t2r, t0i + t2i);
      z[base + Q]     = make_float2(t1r - t3i, t1i + t3r);  // t1 + i t3
      z[base + 2 * Q] = make_float2(t0r - t2r, t0i - t2i);
      z[base + 3 * Q] = make_float2(t1r + t3i, t1i - t3r);  // t1 - i t3
    }
    __syncthreads();
  }
  // ---- inverse radix-2 DIT stage (half=1024, conj twiddle) ----
  for (int bf = tid; bf < 1024; bf += 256) {
    const float2 t = tw[1024 + bf];
    const float2 u = z[bf];
    const float2 v = z[bf + 1024];
    const float vr = v.x * t.x + v.y * t.y;
    const float vi = v.y * t.x - v.x * t.y;
    z[bf] = make_float2(u.x + vr, u.y + vi);
    z[bf + 1024] = make_float2(u.x - vr, u.y - vi);
  }
  __syncthreads();
  // ---- epilogue: phase for o1, amp for o2; x1,x2 still in registers ----
  float* out1 = filt + ((size_t)n * NF + o1) * TT;
  float* out2 = filt + ((size_t)n * NF + o2) * TT;
  const float invN = 1.0f / 2048.0f;
  float phA[4], phB[4], amA[4], amB[4];
#pragma unroll
  for (int r = 0; r < 4; ++r) {
    float2 wvA = z[bA + r];
    float h1 = wvA.y * invN - acc2A[r];
    float h2 = acc1A[r] - wvA.x * invN;
    phA[r] = atan2f(h1, acc1A[r]);
    amA[r] = sqrtf(fmaf(acc2A[r], acc2A[r], h2 * h2));
    float2 wvB = z[bB + r];
    float g1 = wvB.y * invN - acc2B[r];
    float g2 = acc1B[r] - wvB.x * invN;
    phB[r] = atan2f(g1, acc1B[r]);
    amB[r] = sqrtf(fmaf(acc2B[r], acc2B[r], g2 * g2));
  }
  *(float4*)&out1[bA] = make_float4(phA[0], phA[1], phA[2], phA[3]);
  *(float4*)&out1[bB] = make_float4(phB[0], phB[1], phB[2], phB[3]);
  *(float4*)&out2[bA] = make_float4(amA[0], amA[1], amA[2], amA[3]);
  *(float4*)&out2[bB] = make_float4(amB[0], amB[1], amB[2], amB[3]);
}

// ---------------------------------------------------------------------------
// Kernel C: binned MI via MFMA (unchanged from R12 — verified 16x16x32
// layouts, 3-way exact bf16 split, counts via ones-row).
// ---------------------------------------------------------------------------
__global__ __launch_bounds__(64) void mi_kernel(const float* __restrict__ filt,
                                                float* __restrict__ mi) {
  __shared__ __align__(16) unsigned int idx32[512];  // 4 bins/dword
  __shared__ float Cs[12][19];
  const int lane = threadIdx.x;
  const int blk = blockIdx.x;           // bc*40 + jp
  const int bc = blk / 40, jp = blk % 40;
  const float* ph = filt + ((size_t)(bc * 4 + jp / 10) * NF + (jp % 10)) * TT;
  for (int g = lane; g < 512; g += 64) {
    float4 v = *(const float4*)&ph[4 * g];
    float vv[4] = {v.x, v.y, v.z, v.w};
    unsigned int packed = 0;
#pragma unroll
    for (int j = 0; j < 4; ++j) {
      int b = (int)floorf((vv[j] + 3.14159274f) / 6.2831855f * 18.0f);
      b = b < 0 ? 0 : (b > 17 ? 17 : b);
      packed |= ((unsigned int)b) << (8 * j);
    }
    idx32[g] = packed;
  }
  __syncthreads();
  const int n16 = lane & 15;    // A row m / B col n / C col
  const int quad = lane >> 4;   // k-quad (0..3)
  const int aband = n16 < 10 ? n16 : 9;
  const int ja = (jp & 3) + 4 * aband;   // scrambled amp row, same s'
  const float* aptr = filt + ((size_t)(bc * 4 + ja / 10) * NF + 10 + (ja % 10)) * TT
                      + quad * 8;
  const bool isAmp = (n16 < 10);
  const bool isOne = (n16 == 10);
  f32x4 acc0 = {0.f, 0.f, 0.f, 0.f};     // bins 0..15
  f32x4 acc1 = {0.f, 0.f, 0.f, 0.f};     // bins 16..17 (cols 16+n16)
  float4 p0 = *(const float4*)(aptr);
  float4 p1 = *(const float4*)(aptr + 4);
  for (int s = 0; s < 64; ++s) {
    float4 c0 = p0, c1 = p1;
    if (s < 63) {
      p0 = *(const float4*)(aptr + (s + 1) * 32);
      p1 = *(const float4*)(aptr + (s + 1) * 32 + 4);
    }
    float a[8] = {c0.x, c0.y, c0.z, c0.w, c1.x, c1.y, c1.z, c1.w};
    short8 ah, am_, al;
#pragma unroll
    for (int j = 0; j < 8; ++j) {
      float v = isAmp ? a[j] : (isOne ? 1.0f : 0.0f);
      unsigned int u = __float_as_uint(v);
      float h = __uint_as_float(u & 0xFFFF0000u);
      float r1 = v - h;                       // exact (<=16 sig bits)
      unsigned int u2 = __float_as_uint(r1);
      float md = __uint_as_float(u2 & 0xFFFF0000u);
      float r2 = r1 - md;                     // exact (<=8 sig bits)
      unsigned int u3 = __float_as_uint(r2);
      ah[j] = (short)(u >> 16);
      am_[j] = (short)(u2 >> 16);
      al[j] = (short)(u3 >> 16);
    }
    const int dw = s * 8 + quad * 2;
    unsigned int d0 = idx32[dw], d1 = idx32[dw + 1];
    short8 b0, b1;
#pragma unroll
    for (int j = 0; j < 8; ++j) {
      unsigned int byte = ((j < 4 ? d0 : d1) >> ((j & 3) * 8)) & 0xFFu;
      b0[j] = (byte == (unsigned int)n16) ? (short)0x3F80 : (short)0;
      b1[j] = (byte == (unsigned int)(n16 + 16)) ? (short)0x3F80 : (short)0;
    }
    acc0 = __builtin_amdgcn_mfma_f32_16x16x32_bf16(ah, b0, acc0, 0, 0, 0);
    acc0 = __builtin_amdgcn_mfma_f32_16x16x32_bf16(am_, b0, acc0, 0, 0, 0);
    acc0 = __builtin_amdgcn_mfma_f32_16x16x32_bf16(al, b0, acc0, 0, 0, 0);
    acc1 = __builtin_amdgcn_mfma_f32_16x16x32_bf16(ah, b1, acc1, 0, 0, 0);
    acc1 = __builtin_amdgcn_mfma_f32_16x16x32_bf16(am_, b1, acc1, 0, 0, 0);
    acc1 = __builtin_amdgcn_mfma_f32_16x16x32_bf16(al, b1, acc1, 0, 0, 0);
  }
#pragma unroll
  for (int r = 0; r < 4; ++r) {
    int row = quad * 4 + r;
    if (row < 11) {
      Cs[row][n16] = acc0[r];
      if (n16 < 2) Cs[row][16 + n16] = acc1[r];
    }
  }
  __syncthreads();
  if (lane < 10) {
    float tot = 0.f, mb_[18];
#pragma unroll
    for (int b = 0; b < 18; ++b) {
      float mb = Cs[lane][b] / fmaxf(Cs[10][b], 1.0f);
      mb_[b] = mb; tot += mb;
    }
    tot = fmaxf(tot, 1e-12f);
    float s = 0.f;
#pragma unroll
    for (int b = 0; b < 18; ++b) {
      float pb = mb_[b] / tot;
      s += pb * logf(fmaxf(pb, 1e-12f));
    }
    const float LOGN = 2.8903717578961645f; // log(18)
    mi[(size_t)blk * 10 + lane] = (LOGN + s) / LOGN;
  }
}

// ---------------------------------------------------------------------------
// Kernel D: mean over the scrambled s' axis -> out (4,8,10,10)
// ---------------------------------------------------------------------------
__global__ void out_kernel(const float* __restrict__ mi, float* __restrict__ out) {
  int i = blockIdx.x * 256 + threadIdx.x;
  if (i < 3200) {
    int a = i % 10, p = (i / 10) % 10, bc = i / 100;
    float s = 0.f;
    for (int sp = 0; sp < 4; ++sp)
      s += mi[((size_t)(bc * 40 + p * 4 + sp)) * 10 + a];
    out[i] = 0.25f * s;
  }
}

extern "C" void kernel_launch(void* const* d_in, const int* in_sizes, int n_in,
                              void* d_out, int out_size, void* d_ws, size_t ws_size,
                              hipStream_t stream) {
  (void)in_sizes; (void)n_in; (void)out_size; (void)ws_size;
  const float* x = (const float*)d_in[0];     // (4,8,4,2048) fp32
  const float* ker = (const float*)d_in[1];   // (20,769) fp32
  float* out = (float*)d_out;                 // 3200 fp32
  float* filt = (float*)d_ws;                 // 128*20*2048 fp32 (~21 MB)
  float* mi = filt + (size_t)NS * NF * TT;    // 12800 fp32

  convhil_kernel<<<NS * 10, 256, 0, stream>>>(x, ker, filt);
  mi_kernel<<<32 * 40, 64, 0, stream>>>(filt, mi);
  out_kernel<<<(3200 + 255) / 256, 256, 0, stream>>>(mi, out);
}